// Round 11
// baseline (190.893 us; speedup 1.0000x reference)
//
#include <hip/hip_runtime.h>
#include <hip/hip_bf16.h>

#define N_NODES 50000
#define N_EDGES 800000
#define D 128
#define BN_EPS 1e-5f
#define ELLW 64            // max in-degree ~40 (Poisson 16); P(>64) negligible
#define PROJ_LDK 136       // padded k-stride (ushorts) to break LDS bank conflicts
#define SPMM_BLOCKS 1564   // 1564*16 slots = 25024 >= 25000 node pairs
#define PROJ_TILES 782     // ceil(50000/64)

#define BINS 128           // node ranges; one single-writer build block each
#define BIN_RANGE 391      // ceil(50000/128); 128*391 = 50048 >= 50000
#define BINCAP 8192        // expected 6250/bin, sigma ~79 -> ~25-sigma slack
#define A_EPT 13           // 256 blk * 256 thr * 13 = 851968 >= 800000
#define A_BLOCKS 256

typedef __attribute__((ext_vector_type(8))) short bf16x8;
typedef __attribute__((ext_vector_type(4))) float f32x4;
typedef __attribute__((ext_vector_type(4))) unsigned u32x4;

__device__ inline float bf_lo(unsigned u) { union { unsigned x; float f; } c; c.x = u << 16; return c.f; }
__device__ inline float bf_hi(unsigned u) { union { unsigned x; float f; } c; c.x = u & 0xffff0000u; return c.f; }
__device__ inline unsigned short f2bf(float f) {
    union { float f; unsigned u; } c; c.f = f;
    unsigned u = c.u;
    u += 0x7fff + ((u >> 16) & 1);   // RNE
    return (unsigned short)(u >> 16);
}
// HW packed f32->bf16 (RNE), 1 inst for 2 values (no builtin on gfx950)
__device__ inline unsigned cvt_pk_bf16(float lo, float hi) {
    unsigned r;
    asm("v_cvt_pk_bf16_f32 %0, %1, %2" : "=v"(r) : "v"(lo), "v"(hi));
    return r;
}

// ---------- fused kernel A||2: bucket (blocks 0..255) + proj (256..1037) ----
// proj is independent of the edge pipeline (norm_src applied later by build's
// in-place h-scale), so bucket and proj share one dispatch.
__global__ __launch_bounds__(256, 2) void bucket_proj_kernel(
        const int* __restrict__ src,
        const int* __restrict__ dst,
        int* __restrict__ gdbase,
        int* __restrict__ gsbase,
        unsigned* __restrict__ dbkt,
        unsigned short* __restrict__ sbkt,
        const float* __restrict__ feat,
        const float* __restrict__ W,
        unsigned short* __restrict__ h) {
    __shared__ int dcnt[BINS], scnt[BINS], dbase[BINS], sbase[BINS];
    __shared__ unsigned short Wt[D * PROJ_LDK];

    const int tid = threadIdx.x;

    if (blockIdx.x < A_BLOCKS) {
        // ---------------- bucket branch: radix-partition edges ----------------
        if (tid < BINS) { dcnt[tid] = 0; scnt[tid] = 0; }
        __syncthreads();

        const int e0 = blockIdx.x * (256 * A_EPT) + tid;
        int s[A_EPT], t[A_EPT], dr[A_EPT], sr[A_EPT];
        #pragma unroll
        for (int k = 0; k < A_EPT; ++k) {
            int e = e0 + k * 256;
            if (e < N_EDGES) { s[k] = src[e]; t[k] = dst[e]; }
            else             { s[k] = -1;     t[k] = -1;     }
        }
        #pragma unroll
        for (int k = 0; k < A_EPT; ++k) {
            if (t[k] >= 0) dr[k] = atomicAdd(&dcnt[t[k] / BIN_RANGE], 1);
            if (s[k] >= 0) sr[k] = atomicAdd(&scnt[s[k] / BIN_RANGE], 1);
        }
        __syncthreads();
        if (tid < BINS) {
            dbase[tid] = atomicAdd(&gdbase[tid], dcnt[tid]);
            sbase[tid] = atomicAdd(&gsbase[tid], scnt[tid]);
        }
        __syncthreads();
        #pragma unroll
        for (int k = 0; k < A_EPT; ++k) {
            if (t[k] >= 0) {
                int bb = t[k] / BIN_RANGE;
                int p = dbase[bb] + dr[k];
                if (p < BINCAP)
                    dbkt[bb * BINCAP + p] = (unsigned)s[k] | ((unsigned)(t[k] - bb * BIN_RANGE) << 16);
            }
            if (s[k] >= 0) {
                int bb = s[k] / BIN_RANGE;
                int p = sbase[bb] + sr[k];
                if (p < BINCAP)
                    sbkt[bb * BINCAP + p] = (unsigned short)(s[k] - bb * BIN_RANGE);
            }
        }
    } else {
        // ---------------- proj branch: h = bf16(feat @ W) via MFMA -----------
        const int tile = blockIdx.x - A_BLOCKS;   // one 64-row tile per block
        const int wave = tid >> 6;
        const int lane = tid & 63;
        const int quad = lane >> 4;
        const int l16  = lane & 15;

        for (int idx = tid; idx < D * D; idx += 256) {
            int k = idx >> 7, d = idx & 127;
            Wt[d * PROJ_LDK + k] = f2bf(W[idx]);
        }
        __syncthreads();

        bf16x8 breg[8][4];
        #pragma unroll
        for (int dt = 0; dt < 8; ++dt)
            #pragma unroll
            for (int kk = 0; kk < 4; ++kk)
                breg[dt][kk] = *(const bf16x8*)&Wt[(dt * 16 + l16) * PROJ_LDK + kk * 32 + quad * 8];

        const int base = tile * 64;
        const int arow = base + wave * 16 + l16;
        const bool rok = arow < N_NODES;

        f32x4 acc[8];
        #pragma unroll
        for (int dt = 0; dt < 8; ++dt) acc[dt] = (f32x4){0.f, 0.f, 0.f, 0.f};

        #pragma unroll
        for (int kk = 0; kk < 4; ++kk) {
            bf16x8 af = (bf16x8){0, 0, 0, 0, 0, 0, 0, 0};
            if (rok) {
                const float4* fp = (const float4*)(feat + (size_t)arow * D + kk * 32 + quad * 8);
                float4 f0 = fp[0], f1 = fp[1];
                unsigned u0 = cvt_pk_bf16(f0.x, f0.y);
                unsigned u1 = cvt_pk_bf16(f0.z, f0.w);
                unsigned u2 = cvt_pk_bf16(f1.x, f1.y);
                unsigned u3 = cvt_pk_bf16(f1.z, f1.w);
                af[0] = (short)(u0 & 0xffff); af[1] = (short)(u0 >> 16);
                af[2] = (short)(u1 & 0xffff); af[3] = (short)(u1 >> 16);
                af[4] = (short)(u2 & 0xffff); af[5] = (short)(u2 >> 16);
                af[6] = (short)(u3 & 0xffff); af[7] = (short)(u3 >> 16);
            }
            #pragma unroll
            for (int dt = 0; dt < 8; ++dt)
                acc[dt] = __builtin_amdgcn_mfma_f32_16x16x32_bf16(af, breg[dt][kk], acc[dt], 0, 0, 0);
        }

        #pragma unroll
        for (int r = 0; r < 4; ++r) {
            int n = base + wave * 16 + quad * 4 + r;
            if (n < N_NODES) {
                unsigned short* hp = h + (size_t)n * D + l16;
                #pragma unroll
                for (int dt = 0; dt < 8; dt += 2) {
                    unsigned pk = cvt_pk_bf16(acc[dt][r], acc[dt + 1][r]);
                    hp[dt * 16]       = (unsigned short)(pk & 0xffff);
                    hp[(dt + 1) * 16] = (unsigned short)(pk >> 16);
                }
            }
        }
    }
}

// ---------- kernel B: single-writer ELL build + in-place h *= norm_src ------
__global__ __launch_bounds__(1024) void build_kernel(const int* __restrict__ gdbase,
                                                     const int* __restrict__ gsbase,
                                                     const unsigned* __restrict__ dbkt,
                                                     const unsigned short* __restrict__ sbkt,
                                                     unsigned short* __restrict__ ell,
                                                     int* __restrict__ cnt,
                                                     unsigned short* __restrict__ h) {
    __shared__ int hist[BIN_RANGE];
    const int tid = threadIdx.x;
    const int bin = blockIdx.x & (BINS - 1);
    const int lo  = bin * BIN_RANGE;

    for (int i = tid; i < BIN_RANGE; i += 1024) hist[i] = 0;
    __syncthreads();

    if (blockIdx.x < BINS) {
        int count = gdbase[bin]; if (count > BINCAP) count = BINCAP;
        const unsigned* bkt = dbkt + bin * BINCAP;
        int i = tid;
        for (; i + 3072 < count; i += 4096) {
            unsigned e0 = bkt[i], e1 = bkt[i + 1024], e2 = bkt[i + 2048], e3 = bkt[i + 3072];
            int r0 = atomicAdd(&hist[e0 >> 16], 1);
            int r1 = atomicAdd(&hist[e1 >> 16], 1);
            int r2 = atomicAdd(&hist[e2 >> 16], 1);
            int r3 = atomicAdd(&hist[e3 >> 16], 1);
            if (r0 < ELLW) ell[(size_t)(lo + (e0 >> 16)) * ELLW + r0] = (unsigned short)(e0 & 0xffffu);
            if (r1 < ELLW) ell[(size_t)(lo + (e1 >> 16)) * ELLW + r1] = (unsigned short)(e1 & 0xffffu);
            if (r2 < ELLW) ell[(size_t)(lo + (e2 >> 16)) * ELLW + r2] = (unsigned short)(e2 & 0xffffu);
            if (r3 < ELLW) ell[(size_t)(lo + (e3 >> 16)) * ELLW + r3] = (unsigned short)(e3 & 0xffffu);
        }
        for (; i < count; i += 1024) {
            unsigned e = bkt[i];
            int r = atomicAdd(&hist[e >> 16], 1);
            if (r < ELLW) ell[(size_t)(lo + (e >> 16)) * ELLW + r] = (unsigned short)(e & 0xffffu);
        }
        __syncthreads();
        for (int j = tid; j < BIN_RANGE; j += 1024)
            if (lo + j < N_NODES) cnt[lo + j] = hist[j];
    } else {
        int count = gsbase[bin]; if (count > BINCAP) count = BINCAP;
        const unsigned short* bkt = sbkt + bin * BINCAP;
        int i = tid;
        for (; i + 3072 < count; i += 4096) {
            int v0 = bkt[i], v1 = bkt[i + 1024], v2 = bkt[i + 2048], v3 = bkt[i + 3072];
            atomicAdd(&hist[v0], 1); atomicAdd(&hist[v1], 1);
            atomicAdd(&hist[v2], 1); atomicAdd(&hist[v3], 1);
        }
        for (; i < count; i += 1024) atomicAdd(&hist[bkt[i]], 1);
        __syncthreads();
        // scale h rows of this src range by rsqrt(max(deg,1)), in place
        for (int idx = tid; idx < BIN_RANGE * 16; idx += 1024) {
            int j = idx >> 4, c = idx & 15;
            int n = lo + j;
            if (n < N_NODES) {
                int dg = hist[j];
                float ns = rsqrtf((float)(dg < 1 ? 1 : dg));
                uint4* hp = (uint4*)(h + (size_t)n * D) + c;
                uint4 v = *hp;
                uint4 o;
                o.x = cvt_pk_bf16(bf_lo(v.x) * ns, bf_hi(v.x) * ns);
                o.y = cvt_pk_bf16(bf_lo(v.y) * ns, bf_hi(v.y) * ns);
                o.z = cvt_pk_bf16(bf_lo(v.z) * ns, bf_hi(v.z) * ns);
                o.w = cvt_pk_bf16(bf_lo(v.w) * ns, bf_hi(v.w) * ns);
                *hp = o;
            }
        }
    }
}

// ---------- kernel 3: SpMM gather (r7 structure + non-temporal loads) -------
// r7/r8/r10 established: per-wave MLP deepening is null-to-negative — the
// constraint is the CU's L1 miss-handling pipeline (3.2M random cache-line
// requests; ~1 line/13cyc/CU at r7's 43.4us), not load issue or BW. These
// gathers have no L1 reuse worth keeping -> nt (non-temporal) loads bypass
// L1 allocation and its miss bookkeeping.
#define ACC8(a, v) { a[0] += bf_lo((v)[0]); a[1] += bf_hi((v)[0]); \
                     a[2] += bf_lo((v)[1]); a[3] += bf_hi((v)[1]); \
                     a[4] += bf_lo((v)[2]); a[5] += bf_hi((v)[2]); \
                     a[6] += bf_lo((v)[3]); a[7] += bf_hi((v)[3]); }
#define LDH(sid) __builtin_nontemporal_load((const u32x4*)(h + (size_t)((sid)) * D + coff))

__global__ __launch_bounds__(256) void spmm_kernel(const int* __restrict__ cnt,
                                                   const unsigned short* __restrict__ ell,
                                                   const unsigned short* __restrict__ h,
                                                   const float* __restrict__ b,
                                                   const float* __restrict__ a1,
                                                   unsigned short* __restrict__ h2,
                                                   float* __restrict__ bn_sum,
                                                   float* __restrict__ bn_sumsq) {
    const int tid  = threadIdx.x;
    const int l16  = tid & 15;
    const int slot = (blockIdx.x * 256 + tid) >> 4;   // pair index
    const size_t coff = (size_t)l16 * 8;

    float lsum[8] = {0,0,0,0,0,0,0,0};
    float lsq[8]  = {0,0,0,0,0,0,0,0};

    if (slot < N_NODES / 2) {
        const int n0 = slot * 2;
        const int n1 = n0 + 1;
        int dgA = cnt[n0], dgB = cnt[n1];
        int endA = (dgA < ELLW) ? dgA : ELLW;
        int endB = (dgB < ELLW) ? dgB : ELLW;
        const unsigned short* rowA = ell + (size_t)n0 * ELLW;
        const unsigned short* rowB = ell + (size_t)n1 * ELLW;

        float accA[8] = {0,0,0,0,0,0,0,0};
        float accB[8] = {0,0,0,0,0,0,0,0};
        int iA = 0, iB = 0;

        // joint 8-batches: 2 row loads then 16 independent gathers in flight
        while (iA + 8 <= endA && iB + 8 <= endB) {
            uint4 ra = *(const uint4*)(rowA + iA);
            uint4 rb = *(const uint4*)(rowB + iB);
            u32x4 g0 = LDH(ra.x & 0xffff), g1 = LDH(ra.x >> 16);
            u32x4 g2 = LDH(ra.y & 0xffff), g3 = LDH(ra.y >> 16);
            u32x4 g4 = LDH(ra.z & 0xffff), g5 = LDH(ra.z >> 16);
            u32x4 g6 = LDH(ra.w & 0xffff), g7 = LDH(ra.w >> 16);
            u32x4 k0 = LDH(rb.x & 0xffff), k1 = LDH(rb.x >> 16);
            u32x4 k2 = LDH(rb.y & 0xffff), k3 = LDH(rb.y >> 16);
            u32x4 k4 = LDH(rb.z & 0xffff), k5 = LDH(rb.z >> 16);
            u32x4 k6 = LDH(rb.w & 0xffff), k7 = LDH(rb.w >> 16);
            ACC8(accA, g0); ACC8(accA, g1); ACC8(accA, g2); ACC8(accA, g3);
            ACC8(accA, g4); ACC8(accA, g5); ACC8(accA, g6); ACC8(accA, g7);
            ACC8(accB, k0); ACC8(accB, k1); ACC8(accB, k2); ACC8(accB, k3);
            ACC8(accB, k4); ACC8(accB, k5); ACC8(accB, k6); ACC8(accB, k7);
            iA += 8; iB += 8;
        }
        for (; iA + 8 <= endA; iA += 8) {
            uint4 ra = *(const uint4*)(rowA + iA);
            u32x4 g0 = LDH(ra.x & 0xffff), g1 = LDH(ra.x >> 16);
            u32x4 g2 = LDH(ra.y & 0xffff), g3 = LDH(ra.y >> 16);
            u32x4 g4 = LDH(ra.z & 0xffff), g5 = LDH(ra.z >> 16);
            u32x4 g6 = LDH(ra.w & 0xffff), g7 = LDH(ra.w >> 16);
            ACC8(accA, g0); ACC8(accA, g1); ACC8(accA, g2); ACC8(accA, g3);
            ACC8(accA, g4); ACC8(accA, g5); ACC8(accA, g6); ACC8(accA, g7);
        }
        for (; iB + 8 <= endB; iB += 8) {
            uint4 rb = *(const uint4*)(rowB + iB);
            u32x4 k0 = LDH(rb.x & 0xffff), k1 = LDH(rb.x >> 16);
            u32x4 k2 = LDH(rb.y & 0xffff), k3 = LDH(rb.y >> 16);
            u32x4 k4 = LDH(rb.z & 0xffff), k5 = LDH(rb.z >> 16);
            u32x4 k6 = LDH(rb.w & 0xffff), k7 = LDH(rb.w >> 16);
            ACC8(accB, k0); ACC8(accB, k1); ACC8(accB, k2); ACC8(accB, k3);
            ACC8(accB, k4); ACC8(accB, k5); ACC8(accB, k6); ACC8(accB, k7);
        }
        for (; iA < endA; ++iA) { u32x4 g = LDH(rowA[iA]); ACC8(accA, g); }
        for (; iB < endB; ++iB) { u32x4 k = LDH(rowB[iB]); ACC8(accB, k); }

        const float alpha = a1[0];
        float bias[8];
        #pragma unroll
        for (int j = 0; j < 8; ++j) bias[j] = b[l16 * 8 + j];

        float ndA = rsqrtf((float)(dgA < 1 ? 1 : dgA));
        float ndB = rsqrtf((float)(dgB < 1 ? 1 : dgB));
        float xA[8], xB[8];
        #pragma unroll
        for (int j = 0; j < 8; ++j) {
            float va = accA[j] * ndA + bias[j];
            va = (va >= 0.f) ? va : alpha * va;
            xA[j] = va; lsum[j] += va; lsq[j] += va * va;
            float vb = accB[j] * ndB + bias[j];
            vb = (vb >= 0.f) ? vb : alpha * vb;
            xB[j] = vb; lsum[j] += vb; lsq[j] += vb * vb;
        }
        uint4 oA, oB;
        oA.x = cvt_pk_bf16(xA[0], xA[1]); oA.y = cvt_pk_bf16(xA[2], xA[3]);
        oA.z = cvt_pk_bf16(xA[4], xA[5]); oA.w = cvt_pk_bf16(xA[6], xA[7]);
        oB.x = cvt_pk_bf16(xB[0], xB[1]); oB.y = cvt_pk_bf16(xB[2], xB[3]);
        oB.z = cvt_pk_bf16(xB[4], xB[5]); oB.w = cvt_pk_bf16(xB[6], xB[7]);
        *(uint4*)(h2 + (size_t)n0 * D + coff) = oA;
        *(uint4*)(h2 + (size_t)n1 * D + coff) = oB;
    }

    // BN partials: reduce across 4 slots in wave, then 4 waves, then atomics
    #pragma unroll
    for (int j = 0; j < 8; ++j) {
        lsum[j] += __shfl_xor(lsum[j], 16);
        lsum[j] += __shfl_xor(lsum[j], 32);
        lsq[j]  += __shfl_xor(lsq[j], 16);
        lsq[j]  += __shfl_xor(lsq[j], 32);
    }
    __shared__ float red[4][256];
    const int wave = tid >> 6;
    const int lane = tid & 63;
    if (lane < 16) {
        #pragma unroll
        for (int j = 0; j < 8; ++j) {
            red[wave][l16 * 16 + j]     = lsum[j];
            red[wave][l16 * 16 + 8 + j] = lsq[j];
        }
    }
    __syncthreads();
    {
        float tot = red[0][tid] + red[1][tid] + red[2][tid] + red[3][tid];
        int l = tid >> 4;
        int v = tid & 15;
        int dim = l * 8 + (v & 7);
        int rep = (blockIdx.x & 3) * D;    // 4-way replicated accumulators
        if (v < 8) atomicAdd(&bn_sum[rep + dim], tot);
        else       atomicAdd(&bn_sumsq[rep + dim], tot);
    }
}

// ---------- kernel 4: BN finalize + PReLU (bf16 in, fp32 out) ----------
__global__ __launch_bounds__(256) void final_kernel(const unsigned short* __restrict__ h2,
                                                    const float* __restrict__ bn_sum,
                                                    const float* __restrict__ bn_sumsq,
                                                    const float* __restrict__ gamma,
                                                    const float* __restrict__ beta,
                                                    const float* __restrict__ a2,
                                                    float* __restrict__ out) {
    int i8 = blockIdx.x * 256 + threadIdx.x;   // one thread per 8 elements
    if (i8 < N_NODES * D / 8) {
        int dbase = (i8 * 8) & (D - 1);
        const float invN = 1.0f / (float)N_NODES;
        const float alpha = a2[0];
        uint4 v = ((const uint4*)h2)[i8];
        float xv[8] = { bf_lo(v.x), bf_hi(v.x), bf_lo(v.y), bf_hi(v.y),
                        bf_lo(v.z), bf_hi(v.z), bf_lo(v.w), bf_hi(v.w) };
        float r[8];
        #pragma unroll
        for (int j = 0; j < 8; ++j) {
            int d = dbase + j;
            float sm = bn_sum[d] + bn_sum[D + d] + bn_sum[2 * D + d] + bn_sum[3 * D + d];
            float sq = bn_sumsq[d] + bn_sumsq[D + d] + bn_sumsq[2 * D + d] + bn_sumsq[3 * D + d];
            float mean = sm * invN;
            float var  = sq * invN - mean * mean;
            float inv  = rsqrtf(var + BN_EPS);
            float t = (xv[j] - mean) * inv * gamma[d] + beta[d];
            r[j] = (t >= 0.f) ? t : alpha * t;
        }
        float4* po = (float4*)(out + (size_t)i8 * 8);
        po[0] = make_float4(r[0], r[1], r[2], r[3]);
        po[1] = make_float4(r[4], r[5], r[6], r[7]);
    }
}

extern "C" void kernel_launch(void* const* d_in, const int* in_sizes, int n_in,
                              void* d_out, int out_size, void* d_ws, size_t ws_size,
                              hipStream_t stream) {
    const float* feat  = (const float*)d_in[0];
    const int*   src   = (const int*)  d_in[1];
    const int*   dst   = (const int*)  d_in[2];
    const float* W     = (const float*)d_in[3];
    const float* b     = (const float*)d_in[4];
    const float* a1    = (const float*)d_in[5];
    const float* gamma = (const float*)d_in[6];
    const float* beta  = (const float*)d_in[7];
    const float* a2    = (const float*)d_in[8];
    float* out = (float*)d_out;

    // Workspace layout (bytes). Only first 5120 B zeroed:
    //   gdbase (512) | gsbase (512) | bn_sum (2048) | bn_sumsq (2048)
    char* ws = (char*)d_ws;
    int*            gdbase    = (int*)(ws + 0);
    int*            gsbase    = (int*)(ws + 512);
    float*          bn_sum    = (float*)(ws + 1024);
    float*          bn_sumsq  = (float*)(ws + 3072);
    int*            cnt       = (int*)(ws + 5120);                // 200192
    unsigned short* ell       = (unsigned short*)(ws + 405120);   // 6.4 MB
    unsigned short* h         = (unsigned short*)(ws + 6805120);  // 12.8 MB bf16
    unsigned short* h2        = (unsigned short*)(ws + 19605120); // 12.8 MB bf16
    unsigned*       dbkt      = (unsigned*)(ws + 32405120);       // 128*8192*4 = 4 MB
    unsigned short* sbkt      = (unsigned short*)(ws + 36599424); // 128*8192*2 = 2 MB

    (void)hipMemsetAsync(ws, 0, 5120, stream);

    // A||2) bucket (256 blocks) concurrent with proj (782 blocks)
    bucket_proj_kernel<<<A_BLOCKS + PROJ_TILES, 256, 0, stream>>>(
        src, dst, gdbase, gsbase, dbkt, sbkt, feat, W, h);

    // B) single-writer ELL build + cnt + in-place h *= rsqrt(out-degree)
    build_kernel<<<2 * BINS, 1024, 0, stream>>>(gdbase, gsbase, dbkt, sbkt,
                                                ell, cnt, h);

    // 3) SpMM gather (r7 structure, nt loads) + BN partials
    spmm_kernel<<<SPMM_BLOCKS, 256, 0, stream>>>(cnt, ell, h, b, a1, h2,
                                                 bn_sum, bn_sumsq);

    // 4) BN finalize + PReLU
    final_kernel<<<(N_NODES * D / 8 + 255) / 256, 256, 0, stream>>>(h2, bn_sum, bn_sumsq,
                                                                    gamma, beta, a2, out);
}

// Round 12
// 190.416 us; speedup vs baseline: 1.0025x; 1.0025x over previous
//
#include <hip/hip_runtime.h>
#include <hip/hip_bf16.h>

#define N_NODES 50000
#define N_EDGES 800000
#define D 128
#define BN_EPS 1e-5f
#define SEGW 32            // per-(node,src-quartile) ELL width; seg deg ~Poisson(4)
#define NSEG 4             // src quartiles; 3.2MB h-quartile fits 4MB XCD L2
#define QDIV 12500         // 50000/4
#define PROJ_LDK 136       // padded k-stride (ushorts) to break LDS bank conflicts
#define SPMM_BLOCKS 1564   // 1564*16 slots = 25024 >= 25000 node pairs
#define PROJ_TILES 782     // ceil(50000/64)

#define BINS 128           // node ranges; one single-writer build block each
#define BIN_RANGE 391      // ceil(50000/128); 128*391 = 50048 >= 50000
#define BINCAP 8192        // expected 6250/bin, sigma ~79 -> ~25-sigma slack
#define A_EPT 13           // 256 blk * 256 thr * 13 = 851968 >= 800000
#define A_BLOCKS 256

typedef __attribute__((ext_vector_type(8))) short bf16x8;
typedef __attribute__((ext_vector_type(4))) float f32x4;

__device__ inline float bf_lo(unsigned u) { union { unsigned x; float f; } c; c.x = u << 16; return c.f; }
__device__ inline float bf_hi(unsigned u) { union { unsigned x; float f; } c; c.x = u & 0xffff0000u; return c.f; }
__device__ inline unsigned short f2bf(float f) {
    union { float f; unsigned u; } c; c.f = f;
    unsigned u = c.u;
    u += 0x7fff + ((u >> 16) & 1);   // RNE
    return (unsigned short)(u >> 16);
}
// HW packed f32->bf16 (RNE), 1 inst for 2 values (no builtin on gfx950)
__device__ inline unsigned cvt_pk_bf16(float lo, float hi) {
    unsigned r;
    asm("v_cvt_pk_bf16_f32 %0, %1, %2" : "=v"(r) : "v"(lo), "v"(hi));
    return r;
}

// ---------- fused kernel A||2: bucket (blocks 0..255) + proj (256..1037) ----
__global__ __launch_bounds__(256, 2) void bucket_proj_kernel(
        const int* __restrict__ src,
        const int* __restrict__ dst,
        int* __restrict__ gdbase,
        int* __restrict__ gsbase,
        unsigned* __restrict__ dbkt,
        unsigned short* __restrict__ sbkt,
        const float* __restrict__ feat,
        const float* __restrict__ W,
        unsigned short* __restrict__ h) {
    __shared__ int dcnt[BINS], scnt[BINS], dbase[BINS], sbase[BINS];
    __shared__ unsigned short Wt[D * PROJ_LDK];

    const int tid = threadIdx.x;

    if (blockIdx.x < A_BLOCKS) {
        // ---------------- bucket branch: radix-partition edges ----------------
        if (tid < BINS) { dcnt[tid] = 0; scnt[tid] = 0; }
        __syncthreads();

        const int e0 = blockIdx.x * (256 * A_EPT) + tid;
        int s[A_EPT], t[A_EPT], dr[A_EPT], sr[A_EPT];
        #pragma unroll
        for (int k = 0; k < A_EPT; ++k) {
            int e = e0 + k * 256;
            if (e < N_EDGES) { s[k] = src[e]; t[k] = dst[e]; }
            else             { s[k] = -1;     t[k] = -1;     }
        }
        #pragma unroll
        for (int k = 0; k < A_EPT; ++k) {
            if (t[k] >= 0) dr[k] = atomicAdd(&dcnt[t[k] / BIN_RANGE], 1);
            if (s[k] >= 0) sr[k] = atomicAdd(&scnt[s[k] / BIN_RANGE], 1);
        }
        __syncthreads();
        if (tid < BINS) {
            dbase[tid] = atomicAdd(&gdbase[tid], dcnt[tid]);
            sbase[tid] = atomicAdd(&gsbase[tid], scnt[tid]);
        }
        __syncthreads();
        #pragma unroll
        for (int k = 0; k < A_EPT; ++k) {
            if (t[k] >= 0) {
                int bb = t[k] / BIN_RANGE;
                int p = dbase[bb] + dr[k];
                if (p < BINCAP)
                    dbkt[bb * BINCAP + p] = (unsigned)s[k] | ((unsigned)(t[k] - bb * BIN_RANGE) << 16);
            }
            if (s[k] >= 0) {
                int bb = s[k] / BIN_RANGE;
                int p = sbase[bb] + sr[k];
                if (p < BINCAP)
                    sbkt[bb * BINCAP + p] = (unsigned short)(s[k] - bb * BIN_RANGE);
            }
        }
    } else {
        // ---------------- proj branch: h = bf16(feat @ W) via MFMA -----------
        const int tile = blockIdx.x - A_BLOCKS;   // one 64-row tile per block
        const int wave = tid >> 6;
        const int lane = tid & 63;
        const int quad = lane >> 4;
        const int l16  = lane & 15;

        for (int idx = tid; idx < D * D; idx += 256) {
            int k = idx >> 7, d = idx & 127;
            Wt[d * PROJ_LDK + k] = f2bf(W[idx]);
        }
        __syncthreads();

        bf16x8 breg[8][4];
        #pragma unroll
        for (int dt = 0; dt < 8; ++dt)
            #pragma unroll
            for (int kk = 0; kk < 4; ++kk)
                breg[dt][kk] = *(const bf16x8*)&Wt[(dt * 16 + l16) * PROJ_LDK + kk * 32 + quad * 8];

        const int base = tile * 64;
        const int arow = base + wave * 16 + l16;
        const bool rok = arow < N_NODES;

        f32x4 acc[8];
        #pragma unroll
        for (int dt = 0; dt < 8; ++dt) acc[dt] = (f32x4){0.f, 0.f, 0.f, 0.f};

        #pragma unroll
        for (int kk = 0; kk < 4; ++kk) {
            bf16x8 af = (bf16x8){0, 0, 0, 0, 0, 0, 0, 0};
            if (rok) {
                const float4* fp = (const float4*)(feat + (size_t)arow * D + kk * 32 + quad * 8);
                float4 f0 = fp[0], f1 = fp[1];
                unsigned u0 = cvt_pk_bf16(f0.x, f0.y);
                unsigned u1 = cvt_pk_bf16(f0.z, f0.w);
                unsigned u2 = cvt_pk_bf16(f1.x, f1.y);
                unsigned u3 = cvt_pk_bf16(f1.z, f1.w);
                af[0] = (short)(u0 & 0xffff); af[1] = (short)(u0 >> 16);
                af[2] = (short)(u1 & 0xffff); af[3] = (short)(u1 >> 16);
                af[4] = (short)(u2 & 0xffff); af[5] = (short)(u2 >> 16);
                af[6] = (short)(u3 & 0xffff); af[7] = (short)(u3 >> 16);
            }
            #pragma unroll
            for (int dt = 0; dt < 8; ++dt)
                acc[dt] = __builtin_amdgcn_mfma_f32_16x16x32_bf16(af, breg[dt][kk], acc[dt], 0, 0, 0);
        }

        #pragma unroll
        for (int r = 0; r < 4; ++r) {
            int n = base + wave * 16 + quad * 4 + r;
            if (n < N_NODES) {
                unsigned short* hp = h + (size_t)n * D + l16;
                #pragma unroll
                for (int dt = 0; dt < 8; dt += 2) {
                    unsigned pk = cvt_pk_bf16(acc[dt][r], acc[dt + 1][r]);
                    hp[dt * 16]       = (unsigned short)(pk & 0xffff);
                    hp[(dt + 1) * 16] = (unsigned short)(pk >> 16);
                }
            }
        }
    }
}

// ---------- kernel B: single-writer seg-ELL build + in-place h scale --------
// dst branch: rank within (node, src-quartile) via LDS atomics on a [391*4]
// histogram; ell4[node][q][SEGW]; counts byte-packed into cnt4[node].
// src branch: out-degree hist, then h *= rsqrt(deg) in place (norm_src fold).
__global__ __launch_bounds__(1024) void build_kernel(const int* __restrict__ gdbase,
                                                     const int* __restrict__ gsbase,
                                                     const unsigned* __restrict__ dbkt,
                                                     const unsigned short* __restrict__ sbkt,
                                                     unsigned short* __restrict__ ell,
                                                     unsigned* __restrict__ cnt4,
                                                     unsigned short* __restrict__ h) {
    __shared__ int hist[BIN_RANGE * NSEG];
    const int tid = threadIdx.x;
    const int bin = blockIdx.x & (BINS - 1);
    const int lo  = bin * BIN_RANGE;

    const int histN = (blockIdx.x < BINS) ? BIN_RANGE * NSEG : BIN_RANGE;
    for (int i = tid; i < histN; i += 1024) hist[i] = 0;
    __syncthreads();

    if (blockIdx.x < BINS) {
        int count = gdbase[bin]; if (count > BINCAP) count = BINCAP;
        const unsigned* bkt = dbkt + bin * BINCAP;
        int i = tid;
        for (; i + 3072 < count; i += 4096) {     // 4-deep MLP unroll
            unsigned e0 = bkt[i], e1 = bkt[i + 1024], e2 = bkt[i + 2048], e3 = bkt[i + 3072];
            int q0 = (int)(e0 & 0xffffu) / QDIV, q1 = (int)(e1 & 0xffffu) / QDIV;
            int q2 = (int)(e2 & 0xffffu) / QDIV, q3 = (int)(e3 & 0xffffu) / QDIV;
            int r0 = atomicAdd(&hist[(e0 >> 16) * NSEG + q0], 1);
            int r1 = atomicAdd(&hist[(e1 >> 16) * NSEG + q1], 1);
            int r2 = atomicAdd(&hist[(e2 >> 16) * NSEG + q2], 1);
            int r3 = atomicAdd(&hist[(e3 >> 16) * NSEG + q3], 1);
            if (r0 < SEGW) ell[((size_t)(lo + (e0 >> 16)) * NSEG + q0) * SEGW + r0] = (unsigned short)(e0 & 0xffffu);
            if (r1 < SEGW) ell[((size_t)(lo + (e1 >> 16)) * NSEG + q1) * SEGW + r1] = (unsigned short)(e1 & 0xffffu);
            if (r2 < SEGW) ell[((size_t)(lo + (e2 >> 16)) * NSEG + q2) * SEGW + r2] = (unsigned short)(e2 & 0xffffu);
            if (r3 < SEGW) ell[((size_t)(lo + (e3 >> 16)) * NSEG + q3) * SEGW + r3] = (unsigned short)(e3 & 0xffffu);
        }
        for (; i < count; i += 1024) {
            unsigned e = bkt[i];
            int q = (int)(e & 0xffffu) / QDIV;
            int r = atomicAdd(&hist[(e >> 16) * NSEG + q], 1);
            if (r < SEGW) ell[((size_t)(lo + (e >> 16)) * NSEG + q) * SEGW + r] = (unsigned short)(e & 0xffffu);
        }
        __syncthreads();
        for (int j = tid; j < BIN_RANGE; j += 1024)
            if (lo + j < N_NODES) {
                unsigned h0 = (unsigned)min(hist[j * NSEG + 0], 255);
                unsigned h1 = (unsigned)min(hist[j * NSEG + 1], 255);
                unsigned h2 = (unsigned)min(hist[j * NSEG + 2], 255);
                unsigned h3 = (unsigned)min(hist[j * NSEG + 3], 255);
                cnt4[lo + j] = h0 | (h1 << 8) | (h2 << 16) | (h3 << 24);
            }
    } else {
        int count = gsbase[bin]; if (count > BINCAP) count = BINCAP;
        const unsigned short* bkt = sbkt + bin * BINCAP;
        int i = tid;
        for (; i + 3072 < count; i += 4096) {
            int v0 = bkt[i], v1 = bkt[i + 1024], v2 = bkt[i + 2048], v3 = bkt[i + 3072];
            atomicAdd(&hist[v0], 1); atomicAdd(&hist[v1], 1);
            atomicAdd(&hist[v2], 1); atomicAdd(&hist[v3], 1);
        }
        for (; i < count; i += 1024) atomicAdd(&hist[bkt[i]], 1);
        __syncthreads();
        // scale h rows of this src range by rsqrt(max(deg,1)), in place
        for (int idx = tid; idx < BIN_RANGE * 16; idx += 1024) {
            int j = idx >> 4, c = idx & 15;
            int n = lo + j;
            if (n < N_NODES) {
                int dg = hist[j];
                float ns = rsqrtf((float)(dg < 1 ? 1 : dg));
                uint4* hp = (uint4*)(h + (size_t)n * D) + c;
                uint4 v = *hp;
                uint4 o;
                o.x = cvt_pk_bf16(bf_lo(v.x) * ns, bf_hi(v.x) * ns);
                o.y = cvt_pk_bf16(bf_lo(v.y) * ns, bf_hi(v.y) * ns);
                o.z = cvt_pk_bf16(bf_lo(v.z) * ns, bf_hi(v.z) * ns);
                o.w = cvt_pk_bf16(bf_lo(v.w) * ns, bf_hi(v.w) * ns);
                *hp = o;
            }
        }
    }
}

// ---------- kernel 3: SpMM gather over src-quartile segments ----------------
// r7-r11 established: per-wave MLP forcing is null-to-negative and L1 bypass
// hurts — the gather is bounded by random-line service latency. This version
// shrinks the ACTIVE footprint: during segment q all gathers target one
// 3.2MB h-quartile (fits per-XCD 4MB L2) -> misses served at L2 not L3
// latency. Plain uint4 loads (r7 style), 4+4 joint batches (seg deg ~4).
#define ACC8(a, v) { a[0] += bf_lo((v).x); a[1] += bf_hi((v).x); \
                     a[2] += bf_lo((v).y); a[3] += bf_hi((v).y); \
                     a[4] += bf_lo((v).z); a[5] += bf_hi((v).z); \
                     a[6] += bf_lo((v).w); a[7] += bf_hi((v).w); }
#define LDH(sid) (*(const uint4*)(h + (size_t)((sid)) * D + coff))

__global__ __launch_bounds__(256) void spmm_kernel(const unsigned* __restrict__ cnt4,
                                                   const unsigned short* __restrict__ ell,
                                                   const unsigned short* __restrict__ h,
                                                   const float* __restrict__ b,
                                                   const float* __restrict__ a1,
                                                   unsigned short* __restrict__ h2,
                                                   float* __restrict__ bn_sum,
                                                   float* __restrict__ bn_sumsq) {
    const int tid  = threadIdx.x;
    const int l16  = tid & 15;
    const int slot = (blockIdx.x * 256 + tid) >> 4;   // pair index
    const size_t coff = (size_t)l16 * 8;

    float lsum[8] = {0,0,0,0,0,0,0,0};
    float lsq[8]  = {0,0,0,0,0,0,0,0};

    if (slot < N_NODES / 2) {
        const int n0 = slot * 2;
        const int n1 = n0 + 1;
        const unsigned pc0 = cnt4[n0], pc1 = cnt4[n1];
        const int dgA = (int)((pc0 & 0xff) + ((pc0 >> 8) & 0xff) + ((pc0 >> 16) & 0xff) + (pc0 >> 24));
        const int dgB = (int)((pc1 & 0xff) + ((pc1 >> 8) & 0xff) + ((pc1 >> 16) & 0xff) + (pc1 >> 24));

        float accA[8] = {0,0,0,0,0,0,0,0};
        float accB[8] = {0,0,0,0,0,0,0,0};

        for (int q = 0; q < NSEG; ++q) {
            int eA = (int)((pc0 >> (8 * q)) & 0xff); if (eA > SEGW) eA = SEGW;
            int eB = (int)((pc1 >> (8 * q)) & 0xff); if (eB > SEGW) eB = SEGW;
            const unsigned short* rowA = ell + ((size_t)n0 * NSEG + q) * SEGW;
            const unsigned short* rowB = ell + ((size_t)n1 * NSEG + q) * SEGW;
            int iA = 0, iB = 0;

            while (iA + 4 <= eA && iB + 4 <= eB) {
                ushort4 ra = *(const ushort4*)(rowA + iA);
                ushort4 rb = *(const ushort4*)(rowB + iB);
                uint4 g0 = LDH(ra.x), g1 = LDH(ra.y), g2 = LDH(ra.z), g3 = LDH(ra.w);
                uint4 k0 = LDH(rb.x), k1 = LDH(rb.y), k2 = LDH(rb.z), k3 = LDH(rb.w);
                ACC8(accA, g0); ACC8(accA, g1); ACC8(accA, g2); ACC8(accA, g3);
                ACC8(accB, k0); ACC8(accB, k1); ACC8(accB, k2); ACC8(accB, k3);
                iA += 4; iB += 4;
            }
            for (; iA + 4 <= eA; iA += 4) {
                ushort4 ra = *(const ushort4*)(rowA + iA);
                uint4 g0 = LDH(ra.x), g1 = LDH(ra.y), g2 = LDH(ra.z), g3 = LDH(ra.w);
                ACC8(accA, g0); ACC8(accA, g1); ACC8(accA, g2); ACC8(accA, g3);
            }
            for (; iB + 4 <= eB; iB += 4) {
                ushort4 rb = *(const ushort4*)(rowB + iB);
                uint4 k0 = LDH(rb.x), k1 = LDH(rb.y), k2 = LDH(rb.z), k3 = LDH(rb.w);
                ACC8(accB, k0); ACC8(accB, k1); ACC8(accB, k2); ACC8(accB, k3);
            }
            for (; iA < eA; ++iA) { uint4 g = LDH(rowA[iA]); ACC8(accA, g); }
            for (; iB < eB; ++iB) { uint4 k = LDH(rowB[iB]); ACC8(accB, k); }
        }

        const float alpha = a1[0];
        float bias[8];
        #pragma unroll
        for (int j = 0; j < 8; ++j) bias[j] = b[l16 * 8 + j];

        float ndA = rsqrtf((float)(dgA < 1 ? 1 : dgA));
        float ndB = rsqrtf((float)(dgB < 1 ? 1 : dgB));
        float xA[8], xB[8];
        #pragma unroll
        for (int j = 0; j < 8; ++j) {
            float va = accA[j] * ndA + bias[j];
            va = (va >= 0.f) ? va : alpha * va;
            xA[j] = va; lsum[j] += va; lsq[j] += va * va;
            float vb = accB[j] * ndB + bias[j];
            vb = (vb >= 0.f) ? vb : alpha * vb;
            xB[j] = vb; lsum[j] += vb; lsq[j] += vb * vb;
        }
        uint4 oA, oB;
        oA.x = cvt_pk_bf16(xA[0], xA[1]); oA.y = cvt_pk_bf16(xA[2], xA[3]);
        oA.z = cvt_pk_bf16(xA[4], xA[5]); oA.w = cvt_pk_bf16(xA[6], xA[7]);
        oB.x = cvt_pk_bf16(xB[0], xB[1]); oB.y = cvt_pk_bf16(xB[2], xB[3]);
        oB.z = cvt_pk_bf16(xB[4], xB[5]); oB.w = cvt_pk_bf16(xB[6], xB[7]);
        *(uint4*)(h2 + (size_t)n0 * D + coff) = oA;
        *(uint4*)(h2 + (size_t)n1 * D + coff) = oB;
    }

    // BN partials: reduce across 4 slots in wave, then 4 waves, then atomics
    #pragma unroll
    for (int j = 0; j < 8; ++j) {
        lsum[j] += __shfl_xor(lsum[j], 16);
        lsum[j] += __shfl_xor(lsum[j], 32);
        lsq[j]  += __shfl_xor(lsq[j], 16);
        lsq[j]  += __shfl_xor(lsq[j], 32);
    }
    __shared__ float red[4][256];
    const int wave = tid >> 6;
    const int lane = tid & 63;
    if (lane < 16) {
        #pragma unroll
        for (int j = 0; j < 8; ++j) {
            red[wave][l16 * 16 + j]     = lsum[j];
            red[wave][l16 * 16 + 8 + j] = lsq[j];
        }
    }
    __syncthreads();
    {
        float tot = red[0][tid] + red[1][tid] + red[2][tid] + red[3][tid];
        int l = tid >> 4;
        int v = tid & 15;
        int dim = l * 8 + (v & 7);
        int rep = (blockIdx.x & 3) * D;    // 4-way replicated accumulators
        if (v < 8) atomicAdd(&bn_sum[rep + dim], tot);
        else       atomicAdd(&bn_sumsq[rep + dim], tot);
    }
}

// ---------- kernel 4: BN finalize + PReLU (bf16 in, fp32 out) ----------
__global__ __launch_bounds__(256) void final_kernel(const unsigned short* __restrict__ h2,
                                                    const float* __restrict__ bn_sum,
                                                    const float* __restrict__ bn_sumsq,
                                                    const float* __restrict__ gamma,
                                                    const float* __restrict__ beta,
                                                    const float* __restrict__ a2,
                                                    float* __restrict__ out) {
    int i8 = blockIdx.x * 256 + threadIdx.x;   // one thread per 8 elements
    if (i8 < N_NODES * D / 8) {
        int dbase = (i8 * 8) & (D - 1);
        const float invN = 1.0f / (float)N_NODES;
        const float alpha = a2[0];
        uint4 v = ((const uint4*)h2)[i8];
        float xv[8] = { bf_lo(v.x), bf_hi(v.x), bf_lo(v.y), bf_hi(v.y),
                        bf_lo(v.z), bf_hi(v.z), bf_lo(v.w), bf_hi(v.w) };
        float r[8];
        #pragma unroll
        for (int j = 0; j < 8; ++j) {
            int d = dbase + j;
            float sm = bn_sum[d] + bn_sum[D + d] + bn_sum[2 * D + d] + bn_sum[3 * D + d];
            float sq = bn_sumsq[d] + bn_sumsq[D + d] + bn_sumsq[2 * D + d] + bn_sumsq[3 * D + d];
            float mean = sm * invN;
            float var  = sq * invN - mean * mean;
            float inv  = rsqrtf(var + BN_EPS);
            float t = (xv[j] - mean) * inv * gamma[d] + beta[d];
            r[j] = (t >= 0.f) ? t : alpha * t;
        }
        float4* po = (float4*)(out + (size_t)i8 * 8);
        po[0] = make_float4(r[0], r[1], r[2], r[3]);
        po[1] = make_float4(r[4], r[5], r[6], r[7]);
    }
}

extern "C" void kernel_launch(void* const* d_in, const int* in_sizes, int n_in,
                              void* d_out, int out_size, void* d_ws, size_t ws_size,
                              hipStream_t stream) {
    const float* feat  = (const float*)d_in[0];
    const int*   src   = (const int*)  d_in[1];
    const int*   dst   = (const int*)  d_in[2];
    const float* W     = (const float*)d_in[3];
    const float* b     = (const float*)d_in[4];
    const float* a1    = (const float*)d_in[5];
    const float* gamma = (const float*)d_in[6];
    const float* beta  = (const float*)d_in[7];
    const float* a2    = (const float*)d_in[8];
    float* out = (float*)d_out;

    // Workspace layout (bytes). Only first 5120 B zeroed:
    //   gdbase (512) | gsbase (512) | bn_sum (2048) | bn_sumsq (2048)
    char* ws = (char*)d_ws;
    int*            gdbase    = (int*)(ws + 0);
    int*            gsbase    = (int*)(ws + 512);
    float*          bn_sum    = (float*)(ws + 1024);
    float*          bn_sumsq  = (float*)(ws + 3072);
    unsigned*       cnt4      = (unsigned*)(ws + 5120);           // 200000
    unsigned short* ell       = (unsigned short*)(ws + 405120);   // 50000*128*2 = 12.8 MB
    unsigned short* h         = (unsigned short*)(ws + 13205120); // 12.8 MB bf16
    unsigned short* h2        = (unsigned short*)(ws + 26005120); // 12.8 MB bf16
    unsigned*       dbkt      = (unsigned*)(ws + 38805120);       // 128*8192*4 = 4 MB
    unsigned short* sbkt      = (unsigned short*)(ws + 42999424); // 128*8192*2 = 2 MB
    // total ~45 MB (workspace is 256 MB per harness poison fill)

    (void)hipMemsetAsync(ws, 0, 5120, stream);

    // A||2) bucket (256 blocks) concurrent with proj (782 blocks)
    bucket_proj_kernel<<<A_BLOCKS + PROJ_TILES, 256, 0, stream>>>(
        src, dst, gdbase, gsbase, dbkt, sbkt, feat, W, h);

    // B) single-writer seg-ELL build + cnt4 + in-place h *= rsqrt(out-degree)
    build_kernel<<<2 * BINS, 1024, 0, stream>>>(gdbase, gsbase, dbkt, sbkt,
                                                ell, cnt4, h);

    // 3) SpMM gather (src-quartile segments, L2-resident phases) + BN partials
    spmm_kernel<<<SPMM_BLOCKS, 256, 0, stream>>>(cnt4, ell, h, b, a1, h2,
                                                 bn_sum, bn_sumsq);

    // 4) BN finalize + PReLU
    final_kernel<<<(N_NODES * D / 8 + 255) / 256, 256, 0, stream>>>(h2, bn_sum, bn_sumsq,
                                                                    gamma, beta, a2, out);
}

// Round 13
// 175.515 us; speedup vs baseline: 1.0876x; 1.0849x over previous
//
#include <hip/hip_runtime.h>
#include <hip/hip_bf16.h>

#define N_NODES 50000
#define N_EDGES 800000
#define D 128
#define BN_EPS 1e-5f
#define ELLW 64            // max in-degree ~40 (Poisson 16); P(>64) negligible
#define PROJ_LDK 136       // padded k-stride (ushorts) to break LDS bank conflicts
#define SPMM_BLOCKS 1564   // 1564*16 slots = 25024 >= 25000 node pairs
#define PROJ_TILES 782     // ceil(50000/64)

#define BINS 128           // node ranges; one single-writer build block each
#define BIN_RANGE 391      // ceil(50000/128); 128*391 = 50048 >= 50000
#define BINCAP 8192        // expected 6250/bin, sigma ~79 -> ~25-sigma slack
#define A_EPT 13           // 256 blk * 256 thr * 13 = 851968 >= 800000
#define A_BLOCKS 256

typedef __attribute__((ext_vector_type(8))) short bf16x8;
typedef __attribute__((ext_vector_type(4))) float f32x4;

__device__ inline float bf_lo(unsigned u) { union { unsigned x; float f; } c; c.x = u << 16; return c.f; }
__device__ inline float bf_hi(unsigned u) { union { unsigned x; float f; } c; c.x = u & 0xffff0000u; return c.f; }
__device__ inline unsigned short f2bf(float f) {
    union { float f; unsigned u; } c; c.f = f;
    unsigned u = c.u;
    u += 0x7fff + ((u >> 16) & 1);   // RNE
    return (unsigned short)(u >> 16);
}
// HW packed f32->bf16 (RNE), 1 inst for 2 values (no builtin on gfx950)
__device__ inline unsigned cvt_pk_bf16(float lo, float hi) {
    unsigned r;
    asm("v_cvt_pk_bf16_f32 %0, %1, %2" : "=v"(r) : "v"(lo), "v"(hi));
    return r;
}

// ---------- fused kernel A||2: bucket (blocks 0..255) + proj (256..1037) ----
// proj is independent of the edge pipeline (norm_src applied later by build's
// in-place h-scale), so bucket and proj share one dispatch.
__global__ __launch_bounds__(256, 2) void bucket_proj_kernel(
        const int* __restrict__ src,
        const int* __restrict__ dst,
        int* __restrict__ gdbase,
        int* __restrict__ gsbase,
        unsigned* __restrict__ dbkt,
        unsigned short* __restrict__ sbkt,
        const float* __restrict__ feat,
        const float* __restrict__ W,
        unsigned short* __restrict__ h) {
    __shared__ int dcnt[BINS], scnt[BINS], dbase[BINS], sbase[BINS];
    __shared__ unsigned short Wt[D * PROJ_LDK];

    const int tid = threadIdx.x;

    if (blockIdx.x < A_BLOCKS) {
        // ---------------- bucket branch: radix-partition edges ----------------
        if (tid < BINS) { dcnt[tid] = 0; scnt[tid] = 0; }
        __syncthreads();

        const int e0 = blockIdx.x * (256 * A_EPT) + tid;
        int s[A_EPT], t[A_EPT], dr[A_EPT], sr[A_EPT];
        #pragma unroll
        for (int k = 0; k < A_EPT; ++k) {
            int e = e0 + k * 256;
            if (e < N_EDGES) { s[k] = src[e]; t[k] = dst[e]; }
            else             { s[k] = -1;     t[k] = -1;     }
        }
        #pragma unroll
        for (int k = 0; k < A_EPT; ++k) {
            if (t[k] >= 0) dr[k] = atomicAdd(&dcnt[t[k] / BIN_RANGE], 1);
            if (s[k] >= 0) sr[k] = atomicAdd(&scnt[s[k] / BIN_RANGE], 1);
        }
        __syncthreads();
        if (tid < BINS) {
            dbase[tid] = atomicAdd(&gdbase[tid], dcnt[tid]);
            sbase[tid] = atomicAdd(&gsbase[tid], scnt[tid]);
        }
        __syncthreads();
        #pragma unroll
        for (int k = 0; k < A_EPT; ++k) {
            if (t[k] >= 0) {
                int bb = t[k] / BIN_RANGE;
                int p = dbase[bb] + dr[k];
                if (p < BINCAP)
                    dbkt[bb * BINCAP + p] = (unsigned)s[k] | ((unsigned)(t[k] - bb * BIN_RANGE) << 16);
            }
            if (s[k] >= 0) {
                int bb = s[k] / BIN_RANGE;
                int p = sbase[bb] + sr[k];
                if (p < BINCAP)
                    sbkt[bb * BINCAP + p] = (unsigned short)(s[k] - bb * BIN_RANGE);
            }
        }
    } else {
        // ---------------- proj branch: h = bf16(feat @ W) via MFMA -----------
        const int tile = blockIdx.x - A_BLOCKS;   // one 64-row tile per block
        const int wave = tid >> 6;
        const int lane = tid & 63;
        const int quad = lane >> 4;
        const int l16  = lane & 15;

        for (int idx = tid; idx < D * D; idx += 256) {
            int k = idx >> 7, d = idx & 127;
            Wt[d * PROJ_LDK + k] = f2bf(W[idx]);
        }
        __syncthreads();

        bf16x8 breg[8][4];
        #pragma unroll
        for (int dt = 0; dt < 8; ++dt)
            #pragma unroll
            for (int kk = 0; kk < 4; ++kk)
                breg[dt][kk] = *(const bf16x8*)&Wt[(dt * 16 + l16) * PROJ_LDK + kk * 32 + quad * 8];

        const int base = tile * 64;
        const int arow = base + wave * 16 + l16;
        const bool rok = arow < N_NODES;

        f32x4 acc[8];
        #pragma unroll
        for (int dt = 0; dt < 8; ++dt) acc[dt] = (f32x4){0.f, 0.f, 0.f, 0.f};

        #pragma unroll
        for (int kk = 0; kk < 4; ++kk) {
            bf16x8 af = (bf16x8){0, 0, 0, 0, 0, 0, 0, 0};
            if (rok) {
                const float4* fp = (const float4*)(feat + (size_t)arow * D + kk * 32 + quad * 8);
                float4 f0 = fp[0], f1 = fp[1];
                unsigned u0 = cvt_pk_bf16(f0.x, f0.y);
                unsigned u1 = cvt_pk_bf16(f0.z, f0.w);
                unsigned u2 = cvt_pk_bf16(f1.x, f1.y);
                unsigned u3 = cvt_pk_bf16(f1.z, f1.w);
                af[0] = (short)(u0 & 0xffff); af[1] = (short)(u0 >> 16);
                af[2] = (short)(u1 & 0xffff); af[3] = (short)(u1 >> 16);
                af[4] = (short)(u2 & 0xffff); af[5] = (short)(u2 >> 16);
                af[6] = (short)(u3 & 0xffff); af[7] = (short)(u3 >> 16);
            }
            #pragma unroll
            for (int dt = 0; dt < 8; ++dt)
                acc[dt] = __builtin_amdgcn_mfma_f32_16x16x32_bf16(af, breg[dt][kk], acc[dt], 0, 0, 0);
        }

        #pragma unroll
        for (int r = 0; r < 4; ++r) {
            int n = base + wave * 16 + quad * 4 + r;
            if (n < N_NODES) {
                unsigned short* hp = h + (size_t)n * D + l16;
                #pragma unroll
                for (int dt = 0; dt < 8; dt += 2) {
                    unsigned pk = cvt_pk_bf16(acc[dt][r], acc[dt + 1][r]);
                    hp[dt * 16]       = (unsigned short)(pk & 0xffff);
                    hp[(dt + 1) * 16] = (unsigned short)(pk >> 16);
                }
            }
        }
    }
}

// ---------- kernel B: single-writer ELL build + in-place h *= norm_src ------
__global__ __launch_bounds__(1024) void build_kernel(const int* __restrict__ gdbase,
                                                     const int* __restrict__ gsbase,
                                                     const unsigned* __restrict__ dbkt,
                                                     const unsigned short* __restrict__ sbkt,
                                                     unsigned short* __restrict__ ell,
                                                     int* __restrict__ cnt,
                                                     unsigned short* __restrict__ h) {
    __shared__ int hist[BIN_RANGE];
    const int tid = threadIdx.x;
    const int bin = blockIdx.x & (BINS - 1);
    const int lo  = bin * BIN_RANGE;

    for (int i = tid; i < BIN_RANGE; i += 1024) hist[i] = 0;
    __syncthreads();

    if (blockIdx.x < BINS) {
        int count = gdbase[bin]; if (count > BINCAP) count = BINCAP;
        const unsigned* bkt = dbkt + bin * BINCAP;
        int i = tid;
        for (; i + 3072 < count; i += 4096) {
            unsigned e0 = bkt[i], e1 = bkt[i + 1024], e2 = bkt[i + 2048], e3 = bkt[i + 3072];
            int r0 = atomicAdd(&hist[e0 >> 16], 1);
            int r1 = atomicAdd(&hist[e1 >> 16], 1);
            int r2 = atomicAdd(&hist[e2 >> 16], 1);
            int r3 = atomicAdd(&hist[e3 >> 16], 1);
            if (r0 < ELLW) ell[(size_t)(lo + (e0 >> 16)) * ELLW + r0] = (unsigned short)(e0 & 0xffffu);
            if (r1 < ELLW) ell[(size_t)(lo + (e1 >> 16)) * ELLW + r1] = (unsigned short)(e1 & 0xffffu);
            if (r2 < ELLW) ell[(size_t)(lo + (e2 >> 16)) * ELLW + r2] = (unsigned short)(e2 & 0xffffu);
            if (r3 < ELLW) ell[(size_t)(lo + (e3 >> 16)) * ELLW + r3] = (unsigned short)(e3 & 0xffffu);
        }
        for (; i < count; i += 1024) {
            unsigned e = bkt[i];
            int r = atomicAdd(&hist[e >> 16], 1);
            if (r < ELLW) ell[(size_t)(lo + (e >> 16)) * ELLW + r] = (unsigned short)(e & 0xffffu);
        }
        __syncthreads();
        for (int j = tid; j < BIN_RANGE; j += 1024)
            if (lo + j < N_NODES) cnt[lo + j] = hist[j];
    } else {
        int count = gsbase[bin]; if (count > BINCAP) count = BINCAP;
        const unsigned short* bkt = sbkt + bin * BINCAP;
        int i = tid;
        for (; i + 3072 < count; i += 4096) {
            int v0 = bkt[i], v1 = bkt[i + 1024], v2 = bkt[i + 2048], v3 = bkt[i + 3072];
            atomicAdd(&hist[v0], 1); atomicAdd(&hist[v1], 1);
            atomicAdd(&hist[v2], 1); atomicAdd(&hist[v3], 1);
        }
        for (; i < count; i += 1024) atomicAdd(&hist[bkt[i]], 1);
        __syncthreads();
        // scale h rows of this src range by rsqrt(max(deg,1)), in place
        for (int idx = tid; idx < BIN_RANGE * 16; idx += 1024) {
            int j = idx >> 4, c = idx & 15;
            int n = lo + j;
            if (n < N_NODES) {
                int dg = hist[j];
                float ns = rsqrtf((float)(dg < 1 ? 1 : dg));
                uint4* hp = (uint4*)(h + (size_t)n * D) + c;
                uint4 v = *hp;
                uint4 o;
                o.x = cvt_pk_bf16(bf_lo(v.x) * ns, bf_hi(v.x) * ns);
                o.y = cvt_pk_bf16(bf_lo(v.y) * ns, bf_hi(v.y) * ns);
                o.z = cvt_pk_bf16(bf_lo(v.z) * ns, bf_hi(v.z) * ns);
                o.w = cvt_pk_bf16(bf_lo(v.w) * ns, bf_hi(v.w) * ns);
                *hp = o;
            }
        }
    }
}

// ---------- kernel 3: SpMM gather (exact r7 structure — empirical optimum) --
// Design-space bracket (r7-r12): batch-MLP reorder null; forced rotation,
// asm+vmcnt(0), nt loads, L2 segmentation all negative. 43.4us = 3.2M random
// 128B line-gathers at ~1 line/13cyc/CU — the cache hierarchy's random-line
// service rate. Structural floor at HIP source level.
#define ACC8(a, v) { a[0] += bf_lo((v).x); a[1] += bf_hi((v).x); \
                     a[2] += bf_lo((v).y); a[3] += bf_hi((v).y); \
                     a[4] += bf_lo((v).z); a[5] += bf_hi((v).z); \
                     a[6] += bf_lo((v).w); a[7] += bf_hi((v).w); }
#define LDH(sid) (*(const uint4*)(h + (size_t)((sid)) * D + coff))

__global__ __launch_bounds__(256) void spmm_kernel(const int* __restrict__ cnt,
                                                   const unsigned short* __restrict__ ell,
                                                   const unsigned short* __restrict__ h,
                                                   const float* __restrict__ b,
                                                   const float* __restrict__ a1,
                                                   unsigned short* __restrict__ h2,
                                                   float* __restrict__ bn_sum,
                                                   float* __restrict__ bn_sumsq) {
    const int tid  = threadIdx.x;
    const int l16  = tid & 15;
    const int slot = (blockIdx.x * 256 + tid) >> 4;   // pair index
    const size_t coff = (size_t)l16 * 8;

    float lsum[8] = {0,0,0,0,0,0,0,0};
    float lsq[8]  = {0,0,0,0,0,0,0,0};

    if (slot < N_NODES / 2) {
        const int n0 = slot * 2;
        const int n1 = n0 + 1;
        int dgA = cnt[n0], dgB = cnt[n1];
        int endA = (dgA < ELLW) ? dgA : ELLW;
        int endB = (dgB < ELLW) ? dgB : ELLW;
        const unsigned short* rowA = ell + (size_t)n0 * ELLW;
        const unsigned short* rowB = ell + (size_t)n1 * ELLW;

        float accA[8] = {0,0,0,0,0,0,0,0};
        float accB[8] = {0,0,0,0,0,0,0,0};
        int iA = 0, iB = 0;

        // joint 8-batches: 2 row loads then 16 independent gathers in flight
        while (iA + 8 <= endA && iB + 8 <= endB) {
            uint4 ra = *(const uint4*)(rowA + iA);
            uint4 rb = *(const uint4*)(rowB + iB);
            uint4 g0 = LDH(ra.x & 0xffff), g1 = LDH(ra.x >> 16);
            uint4 g2 = LDH(ra.y & 0xffff), g3 = LDH(ra.y >> 16);
            uint4 g4 = LDH(ra.z & 0xffff), g5 = LDH(ra.z >> 16);
            uint4 g6 = LDH(ra.w & 0xffff), g7 = LDH(ra.w >> 16);
            uint4 k0 = LDH(rb.x & 0xffff), k1 = LDH(rb.x >> 16);
            uint4 k2 = LDH(rb.y & 0xffff), k3 = LDH(rb.y >> 16);
            uint4 k4 = LDH(rb.z & 0xffff), k5 = LDH(rb.z >> 16);
            uint4 k6 = LDH(rb.w & 0xffff), k7 = LDH(rb.w >> 16);
            ACC8(accA, g0); ACC8(accA, g1); ACC8(accA, g2); ACC8(accA, g3);
            ACC8(accA, g4); ACC8(accA, g5); ACC8(accA, g6); ACC8(accA, g7);
            ACC8(accB, k0); ACC8(accB, k1); ACC8(accB, k2); ACC8(accB, k3);
            ACC8(accB, k4); ACC8(accB, k5); ACC8(accB, k6); ACC8(accB, k7);
            iA += 8; iB += 8;
        }
        for (; iA + 8 <= endA; iA += 8) {
            uint4 ra = *(const uint4*)(rowA + iA);
            uint4 g0 = LDH(ra.x & 0xffff), g1 = LDH(ra.x >> 16);
            uint4 g2 = LDH(ra.y & 0xffff), g3 = LDH(ra.y >> 16);
            uint4 g4 = LDH(ra.z & 0xffff), g5 = LDH(ra.z >> 16);
            uint4 g6 = LDH(ra.w & 0xffff), g7 = LDH(ra.w >> 16);
            ACC8(accA, g0); ACC8(accA, g1); ACC8(accA, g2); ACC8(accA, g3);
            ACC8(accA, g4); ACC8(accA, g5); ACC8(accA, g6); ACC8(accA, g7);
        }
        for (; iB + 8 <= endB; iB += 8) {
            uint4 rb = *(const uint4*)(rowB + iB);
            uint4 k0 = LDH(rb.x & 0xffff), k1 = LDH(rb.x >> 16);
            uint4 k2 = LDH(rb.y & 0xffff), k3 = LDH(rb.y >> 16);
            uint4 k4 = LDH(rb.z & 0xffff), k5 = LDH(rb.z >> 16);
            uint4 k6 = LDH(rb.w & 0xffff), k7 = LDH(rb.w >> 16);
            ACC8(accB, k0); ACC8(accB, k1); ACC8(accB, k2); ACC8(accB, k3);
            ACC8(accB, k4); ACC8(accB, k5); ACC8(accB, k6); ACC8(accB, k7);
        }
        for (; iA < endA; ++iA) { uint4 g = LDH(rowA[iA]); ACC8(accA, g); }
        for (; iB < endB; ++iB) { uint4 k = LDH(rowB[iB]); ACC8(accB, k); }

        const float alpha = a1[0];
        float bias[8];
        #pragma unroll
        for (int j = 0; j < 8; ++j) bias[j] = b[l16 * 8 + j];

        float ndA = rsqrtf((float)(dgA < 1 ? 1 : dgA));
        float ndB = rsqrtf((float)(dgB < 1 ? 1 : dgB));
        float xA[8], xB[8];
        #pragma unroll
        for (int j = 0; j < 8; ++j) {
            float va = accA[j] * ndA + bias[j];
            va = (va >= 0.f) ? va : alpha * va;
            xA[j] = va; lsum[j] += va; lsq[j] += va * va;
            float vb = accB[j] * ndB + bias[j];
            vb = (vb >= 0.f) ? vb : alpha * vb;
            xB[j] = vb; lsum[j] += vb; lsq[j] += vb * vb;
        }
        uint4 oA, oB;
        oA.x = cvt_pk_bf16(xA[0], xA[1]); oA.y = cvt_pk_bf16(xA[2], xA[3]);
        oA.z = cvt_pk_bf16(xA[4], xA[5]); oA.w = cvt_pk_bf16(xA[6], xA[7]);
        oB.x = cvt_pk_bf16(xB[0], xB[1]); oB.y = cvt_pk_bf16(xB[2], xB[3]);
        oB.z = cvt_pk_bf16(xB[4], xB[5]); oB.w = cvt_pk_bf16(xB[6], xB[7]);
        *(uint4*)(h2 + (size_t)n0 * D + coff) = oA;
        *(uint4*)(h2 + (size_t)n1 * D + coff) = oB;
    }

    // BN partials: reduce across 4 slots in wave, then 4 waves, then atomics
    #pragma unroll
    for (int j = 0; j < 8; ++j) {
        lsum[j] += __shfl_xor(lsum[j], 16);
        lsum[j] += __shfl_xor(lsum[j], 32);
        lsq[j]  += __shfl_xor(lsq[j], 16);
        lsq[j]  += __shfl_xor(lsq[j], 32);
    }
    __shared__ float red[4][256];
    const int wave = tid >> 6;
    const int lane = tid & 63;
    if (lane < 16) {
        #pragma unroll
        for (int j = 0; j < 8; ++j) {
            red[wave][l16 * 16 + j]     = lsum[j];
            red[wave][l16 * 16 + 8 + j] = lsq[j];
        }
    }
    __syncthreads();
    {
        float tot = red[0][tid] + red[1][tid] + red[2][tid] + red[3][tid];
        int l = tid >> 4;
        int v = tid & 15;
        int dim = l * 8 + (v & 7);
        int rep = (blockIdx.x & 3) * D;    // 4-way replicated accumulators
        if (v < 8) atomicAdd(&bn_sum[rep + dim], tot);
        else       atomicAdd(&bn_sumsq[rep + dim], tot);
    }
}

// ---------- kernel 4: BN finalize + PReLU (bf16 in, fp32 out) ----------
__global__ __launch_bounds__(256) void final_kernel(const unsigned short* __restrict__ h2,
                                                    const float* __restrict__ bn_sum,
                                                    const float* __restrict__ bn_sumsq,
                                                    const float* __restrict__ gamma,
                                                    const float* __restrict__ beta,
                                                    const float* __restrict__ a2,
                                                    float* __restrict__ out) {
    int i8 = blockIdx.x * 256 + threadIdx.x;   // one thread per 8 elements
    if (i8 < N_NODES * D / 8) {
        int dbase = (i8 * 8) & (D - 1);
        const float invN = 1.0f / (float)N_NODES;
        const float alpha = a2[0];
        uint4 v = ((const uint4*)h2)[i8];
        float xv[8] = { bf_lo(v.x), bf_hi(v.x), bf_lo(v.y), bf_hi(v.y),
                        bf_lo(v.z), bf_hi(v.z), bf_lo(v.w), bf_hi(v.w) };
        float r[8];
        #pragma unroll
        for (int j = 0; j < 8; ++j) {
            int d = dbase + j;
            float sm = bn_sum[d] + bn_sum[D + d] + bn_sum[2 * D + d] + bn_sum[3 * D + d];
            float sq = bn_sumsq[d] + bn_sumsq[D + d] + bn_sumsq[2 * D + d] + bn_sumsq[3 * D + d];
            float mean = sm * invN;
            float var  = sq * invN - mean * mean;
            float inv  = rsqrtf(var + BN_EPS);
            float t = (xv[j] - mean) * inv * gamma[d] + beta[d];
            r[j] = (t >= 0.f) ? t : alpha * t;
        }
        float4* po = (float4*)(out + (size_t)i8 * 8);
        po[0] = make_float4(r[0], r[1], r[2], r[3]);
        po[1] = make_float4(r[4], r[5], r[6], r[7]);
    }
}

extern "C" void kernel_launch(void* const* d_in, const int* in_sizes, int n_in,
                              void* d_out, int out_size, void* d_ws, size_t ws_size,
                              hipStream_t stream) {
    const float* feat  = (const float*)d_in[0];
    const int*   src   = (const int*)  d_in[1];
    const int*   dst   = (const int*)  d_in[2];
    const float* W     = (const float*)d_in[3];
    const float* b     = (const float*)d_in[4];
    const float* a1    = (const float*)d_in[5];
    const float* gamma = (const float*)d_in[6];
    const float* beta  = (const float*)d_in[7];
    const float* a2    = (const float*)d_in[8];
    float* out = (float*)d_out;

    // Workspace layout (bytes). Only first 5120 B zeroed:
    //   gdbase (512) | gsbase (512) | bn_sum (2048) | bn_sumsq (2048)
    char* ws = (char*)d_ws;
    int*            gdbase    = (int*)(ws + 0);
    int*            gsbase    = (int*)(ws + 512);
    float*          bn_sum    = (float*)(ws + 1024);
    float*          bn_sumsq  = (float*)(ws + 3072);
    int*            cnt       = (int*)(ws + 5120);                // 200192
    unsigned short* ell       = (unsigned short*)(ws + 405120);   // 6.4 MB
    unsigned short* h         = (unsigned short*)(ws + 6805120);  // 12.8 MB bf16
    unsigned short* h2        = (unsigned short*)(ws + 19605120); // 12.8 MB bf16
    unsigned*       dbkt      = (unsigned*)(ws + 32405120);       // 128*8192*4 = 4 MB
    unsigned short* sbkt      = (unsigned short*)(ws + 36599424); // 128*8192*2 = 2 MB

    (void)hipMemsetAsync(ws, 0, 5120, stream);

    // A||2) bucket (256 blocks) concurrent with proj (782 blocks)
    bucket_proj_kernel<<<A_BLOCKS + PROJ_TILES, 256, 0, stream>>>(
        src, dst, gdbase, gsbase, dbkt, sbkt, feat, W, h);

    // B) single-writer ELL build + cnt + in-place h *= rsqrt(out-degree)
    build_kernel<<<2 * BINS, 1024, 0, stream>>>(gdbase, gsbase, dbkt, sbkt,
                                                ell, cnt, h);

    // 3) SpMM gather (r7 structure — empirical optimum) + BN partials
    spmm_kernel<<<SPMM_BLOCKS, 256, 0, stream>>>(cnt, ell, h, b, a1, h2,
                                                 bn_sum, bn_sumsq);

    // 4) BN finalize + PReLU
    final_kernel<<<(N_NODES * D / 8 + 255) / 256, 256, 0, stream>>>(h2, bn_sum, bn_sumsq,
                                                                    gamma, beta, a2, out);
}